// Round 8
// baseline (327.884 us; speedup 1.0000x reference)
//
#include <hip/hip_runtime.h>
#include <stdint.h>

// ---------------- problem constants ----------------
#define N_TOK 8192      // B*S = 4*2048
#define DIM   512       // D
#define HID   1024      // H
#define NE    8         // experts
#define NSLOT 16384     // N_TOK * K (K=2)
#define MAXSLOT 17408   // padded slots (<= 136*128)

typedef __attribute__((ext_vector_type(8))) short short8;   // 8 x bf16 (4 VGPRs)
typedef __attribute__((ext_vector_type(4))) float f32x4;    // MFMA C/D frag

// ---------------- workspace layout (bytes) ----------------
#define W1T_OFF  0ull
#define W2T_OFF  8388608ull
#define H_OFF    16777216ull          // 17408*1024*2 = 35651584
#define Y_OFF    52428800ull          // 17408*512*2  = 17825792
#define XBF_OFF  52428800ull          // alias of Y (xbf dead before gemm2 writes y)
#define TOPI_OFF 70254592ull
#define TOPW_OFF 70320128ull
#define SLOT_OFF 70385664ull
#define ROWS_OFF 70451200ull
#define RW_OFF   70520832ull
#define CNT_OFF  70590464ull

__device__ __forceinline__ unsigned int f2bfu(float f) {
  union { float f; unsigned int i; } v; v.f = f;
  unsigned int u = v.i;
  return (u + 0x7FFFu + ((u >> 16) & 1u)) >> 16;  // RNE, bf16 bits in low 16
}
__device__ __forceinline__ float bf2f(unsigned int u) {
  union { unsigned int i; float f; } v; v.i = (u & 0xFFFFu) << 16; return v.f;
}
// fast GELU: x*sigmoid(1.5957691*x*(1+0.044715*x^2)); max |err| vs erf-GELU ~3e-4
__device__ __forceinline__ float gelu_f(float x) {
  float x2 = x * x;
  float u = x * (1.59576912f + 0.07135481f * x2);
  float ez = __expf(-u);
  return x * __builtin_amdgcn_rcpf(1.0f + ez);
}

// ================= 1. weight transpose + downcast =================
__global__ __launch_bounds__(256) void k_transpose(
    const float* __restrict__ w1, const float* __restrict__ w2,
    unsigned short* __restrict__ w1t, unsigned short* __restrict__ w2t) {
  __shared__ unsigned short tile[64][68];   // +4 pad breaks bank conflicts
  int b = blockIdx.x, tid = threadIdx.x;
  const float* src; unsigned short* dst; int R, C;
  if (b < 1024) { int e = b >> 7; int t = b & 127;
    src = w1 + (size_t)e * 524288; dst = w1t + (size_t)e * 524288; R = 512; C = 1024;
    int tr = t >> 4, tc = t & 15;  // 8 x 16 tiles of 64x64
    src += (size_t)tr * 64 * C + tc * 64; dst += (size_t)tc * 64 * R + tr * 64;
  } else { b -= 1024; int e = b >> 7; int t = b & 127;
    src = w2 + (size_t)e * 524288; dst = w2t + (size_t)e * 524288; R = 1024; C = 512;
    int tr = t >> 3, tc = t & 7;   // 16 x 8 tiles
    src += (size_t)tr * 64 * C + tc * 64; dst += (size_t)tc * 64 * R + tr * 64;
  }
#pragma unroll
  for (int i = 0; i < 4; ++i) {
    int l = i * 256 + tid;
    int r = l >> 4, c4 = (l & 15) << 2;
    float4 v = *(const float4*)(src + (size_t)r * C + c4);
    tile[r][c4 + 0] = (unsigned short)f2bfu(v.x);
    tile[r][c4 + 1] = (unsigned short)f2bfu(v.y);
    tile[r][c4 + 2] = (unsigned short)f2bfu(v.z);
    tile[r][c4 + 3] = (unsigned short)f2bfu(v.w);
  }
  __syncthreads();
#pragma unroll
  for (int i = 0; i < 4; ++i) {
    int l = i * 256 + tid;
    int rr = l >> 4, c4 = (l & 15) << 2;
    ushort4 v;
    v.x = tile[c4 + 0][rr]; v.y = tile[c4 + 1][rr]; v.z = tile[c4 + 2][rr]; v.w = tile[c4 + 3][rr];
    *(ushort4*)(dst + (size_t)rr * R + c4) = v;
  }
}

// ================= 2. router: one wave per token; also emits xbf =================
__global__ __launch_bounds__(256) void k_router(
    const float* __restrict__ x, const float* __restrict__ gw,
    const float* __restrict__ gb, float* __restrict__ probs_out,
    int2* __restrict__ topi, float2* __restrict__ topw,
    unsigned short* __restrict__ xbf) {
  int wave = threadIdx.x >> 6, lane = threadIdx.x & 63;
  int n = blockIdx.x * 4 + wave;
  const float4* xr = (const float4*)(x + (size_t)n * DIM);
  float4 x0 = xr[lane * 2], x1 = xr[lane * 2 + 1];
  float xf[8] = {x0.x, x0.y, x0.z, x0.w, x1.x, x1.y, x1.z, x1.w};
  uint4 pa;
  pa.x = f2bfu(xf[0]) | (f2bfu(xf[1]) << 16);
  pa.y = f2bfu(xf[2]) | (f2bfu(xf[3]) << 16);
  pa.z = f2bfu(xf[4]) | (f2bfu(xf[5]) << 16);
  pa.w = f2bfu(xf[6]) | (f2bfu(xf[7]) << 16);
  *(uint4*)(xbf + (size_t)n * DIM + lane * 8) = pa;
  float acc[8] = {0.f,0.f,0.f,0.f,0.f,0.f,0.f,0.f};
  const float4* gwr = (const float4*)gw;
#pragma unroll
  for (int j = 0; j < 8; ++j) {
    int d = lane * 8 + j;
    float4 g0 = gwr[d * 2], g1 = gwr[d * 2 + 1];
    acc[0] += xf[j] * g0.x; acc[1] += xf[j] * g0.y; acc[2] += xf[j] * g0.z; acc[3] += xf[j] * g0.w;
    acc[4] += xf[j] * g1.x; acc[5] += xf[j] * g1.y; acc[6] += xf[j] * g1.z; acc[7] += xf[j] * g1.w;
  }
#pragma unroll
  for (int o = 1; o < 64; o <<= 1)
#pragma unroll
    for (int e = 0; e < 8; ++e) acc[e] += __shfl_xor(acc[e], o, 64);
  float p[8], mx = -1e30f, s = 0.f;
#pragma unroll
  for (int e = 0; e < 8; ++e) { p[e] = acc[e] + gb[e]; mx = fmaxf(mx, p[e]); }
#pragma unroll
  for (int e = 0; e < 8; ++e) { p[e] = __expf(p[e] - mx); s += p[e]; }
  float inv = 1.f / s;
#pragma unroll
  for (int e = 0; e < 8; ++e) p[e] *= inv;
  if (lane < 8) probs_out[(size_t)n * NE + lane] = p[lane];
  if (lane == 0) {
    int i0 = 0; float v0 = p[0];
#pragma unroll
    for (int e = 1; e < 8; ++e) if (p[e] > v0) { v0 = p[e]; i0 = e; }   // first-max (jax tie rule)
    int i1 = -1; float v1 = -1.f;
#pragma unroll
    for (int e = 0; e < 8; ++e) if (e != i0 && p[e] > v1) { v1 = p[e]; i1 = e; }
    float sw = 1.f / (v0 + v1);
    topi[n] = make_int2(i0, i1);
    topw[n] = make_float2(v0 * sw, v1 * sw);
  }
}

// ================= 3. count: histogram + padded scan + tile map + pad fill =================
__global__ __launch_bounds__(1024) void k_count(
    const int2* __restrict__ topi, int* __restrict__ meta, int* __restrict__ chunk_base,
    int* __restrict__ rows, float* __restrict__ rw) {
  __shared__ int ch[32][8];
  __shared__ int tot[8], poff_s[9], tiles_s[8];
  int t = threadIdx.x;
  int g = t >> 5;
  if (t < 256) ((int*)ch)[t] = 0;
  __syncthreads();
  int c[8] = {0,0,0,0,0,0,0,0};
  int base_tok = t * 8;
#pragma unroll
  for (int i = 0; i < 8; ++i) {
    int2 e = topi[base_tok + i];
#pragma unroll
    for (int k = 0; k < 8; ++k) c[k] += (e.x == k) + (e.y == k);
  }
#pragma unroll
  for (int k = 0; k < 8; ++k) if (c[k]) atomicAdd(&ch[g][k], c[k]);
  __syncthreads();
  if (t < 8) {
    int a = 0;
#pragma unroll
    for (int b = 0; b < 32; ++b) { int v = ch[b][t]; ch[b][t] = a; a += v; }
    tot[t] = a; meta[t] = a;
  }
  __syncthreads();
  if (t == 0) {
    int a = 0, ts = 0;
#pragma unroll
    for (int e = 0; e < 8; ++e) {
      int tiles = (tot[e] + 127) >> 7;
      poff_s[e] = a; tiles_s[e] = tiles;
      meta[16 + e] = a; meta[32 + e] = ts;
      a += tiles << 7; ts += tiles;
    }
    poff_s[8] = a; meta[24] = a; meta[40] = ts;
  }
  __syncthreads();
  if (t < 256) {
    int b = t >> 3, e = t & 7;
    chunk_base[t] = poff_s[e] + ch[b][e];
  }
#pragma unroll
  for (int e = 0; e < 8; ++e) {
    int padn = (tiles_s[e] << 7) - tot[e];
    if (t < padn) {
      int s = poff_s[e] + tot[e] + t;
      rows[s] = 0; rw[s] = 0.f;
    }
  }
}

// ================= 4. slot assignment: LDS atomics only =================
__global__ __launch_bounds__(256) void k_assign(
    const int2* __restrict__ topi, const float2* __restrict__ topw,
    const int* __restrict__ chunk_base,
    int* __restrict__ rows, float* __restrict__ rw, int* __restrict__ slot_of) {
  __shared__ int lcnt[8];
  __shared__ int lbase[8];
  int t = threadIdx.x, b = blockIdx.x;
  if (t < 8) { lcnt[t] = 0; lbase[t] = chunk_base[b * 8 + t]; }
  __syncthreads();
  int n = b * 256 + t;
  int2 ei = topi[n]; float2 wv = topw[n];
  int r0 = atomicAdd(&lcnt[ei.x], 1);
  int r1 = atomicAdd(&lcnt[ei.y], 1);
  int s0 = lbase[ei.x] + r0;
  int s1 = lbase[ei.y] + r1;
  rows[s0] = n; rw[s0] = wv.x; slot_of[2 * n] = s0;
  rows[s1] = n; rw[s1] = wv.y; slot_of[2 * n + 1] = s1;
}

// ================= 5. GEMM1: h = gelu(gather(xbf) @ w1 + b1), h bf16 =================
// grid (8=nt fastest -> XCD-local weight slice, 136=tile). 128x128, BK=64.
// Register-prefetch pipeline: global->VGPR one tile ahead; ds_write after compute
// consumes vmcnt, so the barrier's vmcnt(0) drain is free (vs async-LDS where the
// barrier drains the prefetch itself).
__global__ __launch_bounds__(256) void k_gemm1(
    const unsigned short* __restrict__ xbf, const unsigned short* __restrict__ w1t,
    const float* __restrict__ b1, const int* __restrict__ meta,
    const int* __restrict__ rows, unsigned short* __restrict__ h) {
  int t = blockIdx.y;
  if (t >= meta[40]) return;
  int e = 0;
#pragma unroll
  for (int i = 1; i < 8; ++i) if (t >= meta[32 + i]) e = i;
  int mt = t - meta[32 + e];
  int row0 = meta[16 + e] + (mt << 7);
  int nt = blockIdx.x;
  __shared__ __align__(16) unsigned short As[2][8192];
  __shared__ __align__(16) unsigned short Bs[2][8192];
  int tid = threadIdx.x;
  int wave = tid >> 6, lane = tid & 63;
  int wr = wave & 1, wc = wave >> 1;
  f32x4 acc[4][4] = {};   // acc[an][am]
  const unsigned short* bBase = w1t + (size_t)e * HID * DIM + (size_t)(nt * 128) * DIM;

  // K-invariant staging addresses + LDS slot offsets (XOR-swizzled, contiguous)
  const unsigned short* ga[4]; const unsigned short* gb[4]; int lofs[4];
#pragma unroll
  for (int j = 0; j < 4; ++j) {
    int s = j * 256 + tid;
    int r = s >> 3;
    int cg = ((s & 7) ^ (r & 7)) << 3;
    ga[j] = xbf + (size_t)rows[row0 + r] * DIM + cg;
    gb[j] = bBase + (size_t)r * DIM + cg;
    lofs[j] = s * 8;
  }

  // prologue: tile 0 -> regs -> LDS[0]
  uint4 pa[4], pb[4];
#pragma unroll
  for (int j = 0; j < 4; ++j) { pa[j] = *(const uint4*)ga[j]; pb[j] = *(const uint4*)gb[j]; }
#pragma unroll
  for (int j = 0; j < 4; ++j) {
    *(uint4*)&As[0][lofs[j]] = pa[j];
    *(uint4*)&Bs[0][lofs[j]] = pb[j];
  }
  __syncthreads();

  for (int k0 = 0; k0 < DIM; k0 += 64) {
    int cur = (k0 >> 6) & 1, nxt = cur ^ 1;
    bool more = (k0 + 64 < DIM);
    if (more) {
#pragma unroll
      for (int j = 0; j < 4; ++j) {        // prefetch tile k+1 into regs (no wait)
        pa[j] = *(const uint4*)(ga[j] + k0 + 64);
        pb[j] = *(const uint4*)(gb[j] + k0 + 64);
      }
    }
#pragma unroll
    for (int kk = 0; kk < 2; ++kk) {
      int ca = kk * 4 + (lane >> 4);       // chunk col for this quad
      short8 tf[4], wf[4];
#pragma unroll
      for (int am = 0; am < 4; ++am) {
        int ra = wr * 64 + am * 16 + (lane & 15);
        tf[am] = *(const short8*)&As[cur][(ra * 8 + (ca ^ (ra & 7))) * 8];
      }
#pragma unroll
      for (int an = 0; an < 4; ++an) {
        int rb = wc * 64 + an * 16 + (lane & 15);
        wf[an] = *(const short8*)&Bs[cur][(rb * 8 + (ca ^ (rb & 7))) * 8];
      }
#pragma unroll
      for (int an = 0; an < 4; ++an)
#pragma unroll
        for (int am = 0; am < 4; ++am)
          acc[an][am] = __builtin_amdgcn_mfma_f32_16x16x32_bf16(wf[an], tf[am], acc[an][am], 0, 0, 0);
    }
    __builtin_amdgcn_sched_barrier(0);     // keep ds_write (and its vmcnt wait) after compute
    if (more) {
#pragma unroll
      for (int j = 0; j < 4; ++j) {
        *(uint4*)&As[nxt][lofs[j]] = pa[j];
        *(uint4*)&Bs[nxt][lofs[j]] = pb[j];
      }
      __syncthreads();
    }
  }
  // epilogue: lane holds token row (lane&15) x 4 consecutive cols (quad*4..+3)
  int ml = lane & 15, q = lane >> 4;
#pragma unroll
  for (int am = 0; am < 4; ++am) {
    int slot_r = row0 + wr * 64 + am * 16 + ml;
    unsigned short* hrow = h + (size_t)slot_r * HID;
#pragma unroll
    for (int an = 0; an < 4; ++an) {
      int colb = nt * 128 + wc * 64 + an * 16 + q * 4;
      float4 bias = *(const float4*)&b1[e * HID + colb];
      f32x4 v = acc[an][am];
      float g0 = gelu_f(v[0] + bias.x);
      float g1 = gelu_f(v[1] + bias.y);
      float g2 = gelu_f(v[2] + bias.z);
      float g3 = gelu_f(v[3] + bias.w);
      uint2 pk;
      pk.x = f2bfu(g0) | (f2bfu(g1) << 16);
      pk.y = f2bfu(g2) | (f2bfu(g3) << 16);
      *(uint2*)(hrow + colb) = pk;
    }
  }
}

// ================= 6. GEMM2: y = (h @ w2 + b2) * weight, y bf16 =================
// grid (4=nt fastest, 136=tile). K = HID = 1024. Same register-prefetch pipeline.
__global__ __launch_bounds__(256) void k_gemm2(
    const unsigned short* __restrict__ h, const unsigned short* __restrict__ w2t,
    const float* __restrict__ b2, const int* __restrict__ meta,
    const float* __restrict__ rw, unsigned short* __restrict__ y) {
  int t = blockIdx.y;
  if (t >= meta[40]) return;
  int e = 0;
#pragma unroll
  for (int i = 1; i < 8; ++i) if (t >= meta[32 + i]) e = i;
  int mt = t - meta[32 + e];
  int row0 = meta[16 + e] + (mt << 7);
  int nt = blockIdx.x;
  __shared__ __align__(16) unsigned short As[2][8192];
  __shared__ __align__(16) unsigned short Bs[2][8192];
  int tid = threadIdx.x;
  int wave = tid >> 6, lane = tid & 63;
  int wr = wave & 1, wc = wave >> 1;
  f32x4 acc[4][4] = {};   // acc[an][am]
  const unsigned short* aBase = h + (size_t)row0 * HID;
  const unsigned short* bBase = w2t + (size_t)e * DIM * HID + (size_t)(nt * 128) * HID;

  const unsigned short* ga[4]; const unsigned short* gb[4]; int lofs[4];
#pragma unroll
  for (int j = 0; j < 4; ++j) {
    int s = j * 256 + tid;
    int r = s >> 3;
    int cg = ((s & 7) ^ (r & 7)) << 3;
    ga[j] = aBase + (size_t)r * HID + cg;
    gb[j] = bBase + (size_t)r * HID + cg;
    lofs[j] = s * 8;
  }

  uint4 pa[4], pb[4];
#pragma unroll
  for (int j = 0; j < 4; ++j) { pa[j] = *(const uint4*)ga[j]; pb[j] = *(const uint4*)gb[j]; }
#pragma unroll
  for (int j = 0; j < 4; ++j) {
    *(uint4*)&As[0][lofs[j]] = pa[j];
    *(uint4*)&Bs[0][lofs[j]] = pb[j];
  }
  __syncthreads();

  for (int k0 = 0; k0 < HID; k0 += 64) {
    int cur = (k0 >> 6) & 1, nxt = cur ^ 1;
    bool more = (k0 + 64 < HID);
    if (more) {
#pragma unroll
      for (int j = 0; j < 4; ++j) {
        pa[j] = *(const uint4*)(ga[j] + k0 + 64);
        pb[j] = *(const uint4*)(gb[j] + k0 + 64);
      }
    }
#pragma unroll
    for (int kk = 0; kk < 2; ++kk) {
      int ca = kk * 4 + (lane >> 4);
      short8 tf[4], wf[4];
#pragma unroll
      for (int am = 0; am < 4; ++am) {
        int ra = wr * 64 + am * 16 + (lane & 15);
        tf[am] = *(const short8*)&As[cur][(ra * 8 + (ca ^ (ra & 7))) * 8];
      }
#pragma unroll
      for (int an = 0; an < 4; ++an) {
        int rb = wc * 64 + an * 16 + (lane & 15);
        wf[an] = *(const short8*)&Bs[cur][(rb * 8 + (ca ^ (rb & 7))) * 8];
      }
#pragma unroll
      for (int an = 0; an < 4; ++an)
#pragma unroll
        for (int am = 0; am < 4; ++am)
          acc[an][am] = __builtin_amdgcn_mfma_f32_16x16x32_bf16(wf[an], tf[am], acc[an][am], 0, 0, 0);
    }
    __builtin_amdgcn_sched_barrier(0);
    if (more) {
#pragma unroll
      for (int j = 0; j < 4; ++j) {
        *(uint4*)&As[nxt][lofs[j]] = pa[j];
        *(uint4*)&Bs[nxt][lofs[j]] = pb[j];
      }
      __syncthreads();
    }
  }
  int ml = lane & 15, q = lane >> 4;
#pragma unroll
  for (int am = 0; am < 4; ++am) {
    int slot_r = row0 + wr * 64 + am * 16 + ml;
    float w = rw[slot_r];
    unsigned short* yrow = y + (size_t)slot_r * DIM;
#pragma unroll
    for (int an = 0; an < 4; ++an) {
      int colb = nt * 128 + wc * 64 + an * 16 + q * 4;
      float4 bias = *(const float4*)&b2[e * DIM + colb];
      f32x4 v = acc[an][am];
      uint2 pk;
      pk.x = f2bfu((v[0] + bias.x) * w) | (f2bfu((v[1] + bias.y) * w) << 16);
      pk.y = f2bfu((v[2] + bias.z) * w) | (f2bfu((v[3] + bias.w) * w) << 16);
      *(uint2*)(yrow + colb) = pk;
    }
  }
}

// ================= 7. combine: out[n] = y[slot0] + y[slot1] (bf16 -> fp32) =================
__global__ __launch_bounds__(256) void k_combine(
    const unsigned short* __restrict__ y, const int* __restrict__ slot_of,
    float* __restrict__ out) {
  int t = blockIdx.x * 256 + threadIdx.x;
  int n = t >> 6, c = (t & 63) << 3;
  int s0 = slot_of[2 * n], s1 = slot_of[2 * n + 1];
  uint4 u0 = *(const uint4*)(y + (size_t)s0 * DIM + c);
  uint4 u1 = *(const uint4*)(y + (size_t)s1 * DIM + c);
  float4 o0, o1;
  o0.x = bf2f(u0.x) + bf2f(u1.x); o0.y = bf2f(u0.x >> 16) + bf2f(u1.x >> 16);
  o0.z = bf2f(u0.y) + bf2f(u1.y); o0.w = bf2f(u0.y >> 16) + bf2f(u1.y >> 16);
  o1.x = bf2f(u0.z) + bf2f(u1.z); o1.y = bf2f(u0.z >> 16) + bf2f(u1.z >> 16);
  o1.z = bf2f(u0.w) + bf2f(u1.w); o1.w = bf2f(u0.w >> 16) + bf2f(u1.w >> 16);
  *(float4*)(out + (size_t)n * DIM + c) = o0;
  *(float4*)(out + (size_t)n * DIM + c + 4) = o1;
}

// ================= launch =================
extern "C" void kernel_launch(void* const* d_in, const int* in_sizes, int n_in,
                              void* d_out, int out_size, void* d_ws, size_t ws_size,
                              hipStream_t stream) {
  const float* x  = (const float*)d_in[0];
  const float* gw = (const float*)d_in[1];
  const float* gb = (const float*)d_in[2];
  const float* w1 = (const float*)d_in[3];
  const float* b1 = (const float*)d_in[4];
  const float* w2 = (const float*)d_in[5];
  const float* b2 = (const float*)d_in[6];
  float* out = (float*)d_out;
  char* ws = (char*)d_ws;

  unsigned short* w1t = (unsigned short*)(ws + W1T_OFF);
  unsigned short* w2t = (unsigned short*)(ws + W2T_OFF);
  unsigned short* h   = (unsigned short*)(ws + H_OFF);
  unsigned short* y   = (unsigned short*)(ws + Y_OFF);
  unsigned short* xbf = (unsigned short*)(ws + XBF_OFF);
  int2*   topi    = (int2*)(ws + TOPI_OFF);
  float2* topw    = (float2*)(ws + TOPW_OFF);
  int*    slot_of = (int*)(ws + SLOT_OFF);
  int*    rows    = (int*)(ws + ROWS_OFF);
  float*  rw      = (float*)(ws + RW_OFF);
  int*    meta    = (int*)(ws + CNT_OFF);
  int*    chunk_base = meta + 64;
  float*  probs   = out + (size_t)N_TOK * DIM;

  k_transpose<<<dim3(2048), dim3(256), 0, stream>>>(w1, w2, w1t, w2t);
  k_router   <<<dim3(2048), dim3(256), 0, stream>>>(x, gw, gb, probs, topi, topw, xbf);
  k_count    <<<dim3(1),    dim3(1024), 0, stream>>>(topi, meta, chunk_base, rows, rw);
  k_assign   <<<dim3(32),   dim3(256), 0, stream>>>(topi, topw, chunk_base, rows, rw, slot_of);
  k_gemm1    <<<dim3(8, 136), dim3(256), 0, stream>>>(xbf, w1t, b1, meta, rows, h);
  k_gemm2    <<<dim3(4, 136), dim3(256), 0, stream>>>(h, w2t, b2, meta, rw, y);
  k_combine  <<<dim3(2048), dim3(256), 0, stream>>>(y, slot_of, out);
}

// Round 9
// 210.361 us; speedup vs baseline: 1.5587x; 1.5587x over previous
//
#include <hip/hip_runtime.h>
#include <stdint.h>

// ---------------- problem constants ----------------
#define N_TOK 8192      // B*S = 4*2048
#define DIM   512       // D
#define HID   1024      // H
#define NE    8         // experts
#define NSLOT 16384     // N_TOK * K (K=2)
#define MAXSLOT 17408   // padded slots (<= 136*128)

typedef __attribute__((ext_vector_type(8))) short short8;   // 8 x bf16 (4 VGPRs)
typedef __attribute__((ext_vector_type(4))) float f32x4;    // MFMA C/D frag

// ---------------- workspace layout (bytes) ----------------
#define W1T_OFF  0ull
#define W2T_OFF  8388608ull
#define H_OFF    16777216ull          // 17408*1024*2 = 35651584
#define Y_OFF    52428800ull          // 17408*512*2  = 17825792
#define XBF_OFF  52428800ull          // alias of Y (xbf dead before gemm2 writes y)
#define TOPI_OFF 70254592ull
#define TOPW_OFF 70320128ull
#define SLOT_OFF 70385664ull
#define ROWS_OFF 70451200ull
#define RW_OFF   70520832ull
#define CNT_OFF  70590464ull

__device__ __forceinline__ unsigned int f2bfu(float f) {
  union { float f; unsigned int i; } v; v.f = f;
  unsigned int u = v.i;
  return (u + 0x7FFFu + ((u >> 16) & 1u)) >> 16;  // RNE, bf16 bits in low 16
}
__device__ __forceinline__ float bf2f(unsigned int u) {
  union { unsigned int i; float f; } v; v.i = (u & 0xFFFFu) << 16; return v.f;
}
// fast GELU: x*sigmoid(1.5957691*x*(1+0.044715*x^2)); max |err| vs erf-GELU ~3e-4
__device__ __forceinline__ float gelu_f(float x) {
  float x2 = x * x;
  float u = x * (1.59576912f + 0.07135481f * x2);
  float ez = __expf(-u);
  return x * __builtin_amdgcn_rcpf(1.0f + ez);
}
// async global->LDS, 16B/lane. LDS dest = wave-uniform base + lane*16.
__device__ __forceinline__ void async16(void* lds, const void* g) {
  __builtin_amdgcn_global_load_lds(
      (const __attribute__((address_space(1))) unsigned int*)g,
      (__attribute__((address_space(3))) unsigned int*)lds, 16, 0, 0);
}

// ================= 1. weight transpose + downcast =================
__global__ __launch_bounds__(256) void k_transpose(
    const float* __restrict__ w1, const float* __restrict__ w2,
    unsigned short* __restrict__ w1t, unsigned short* __restrict__ w2t) {
  __shared__ unsigned short tile[64][68];   // +4 pad breaks bank conflicts
  int b = blockIdx.x, tid = threadIdx.x;
  const float* src; unsigned short* dst; int R, C;
  if (b < 1024) { int e = b >> 7; int t = b & 127;
    src = w1 + (size_t)e * 524288; dst = w1t + (size_t)e * 524288; R = 512; C = 1024;
    int tr = t >> 4, tc = t & 15;  // 8 x 16 tiles of 64x64
    src += (size_t)tr * 64 * C + tc * 64; dst += (size_t)tc * 64 * R + tr * 64;
  } else { b -= 1024; int e = b >> 7; int t = b & 127;
    src = w2 + (size_t)e * 524288; dst = w2t + (size_t)e * 524288; R = 1024; C = 512;
    int tr = t >> 3, tc = t & 7;   // 16 x 8 tiles
    src += (size_t)tr * 64 * C + tc * 64; dst += (size_t)tc * 64 * R + tr * 64;
  }
#pragma unroll
  for (int i = 0; i < 4; ++i) {
    int l = i * 256 + tid;
    int r = l >> 4, c4 = (l & 15) << 2;
    float4 v = *(const float4*)(src + (size_t)r * C + c4);
    tile[r][c4 + 0] = (unsigned short)f2bfu(v.x);
    tile[r][c4 + 1] = (unsigned short)f2bfu(v.y);
    tile[r][c4 + 2] = (unsigned short)f2bfu(v.z);
    tile[r][c4 + 3] = (unsigned short)f2bfu(v.w);
  }
  __syncthreads();
#pragma unroll
  for (int i = 0; i < 2; ++i) {           // 16B stores: 512 chunks of 8
    int l = i * 256 + tid;
    int rr = l >> 3, c8 = (l & 7) << 3;
    ushort4 a, b2v;
    a.x = tile[c8 + 0][rr]; a.y = tile[c8 + 1][rr];
    a.z = tile[c8 + 2][rr]; a.w = tile[c8 + 3][rr];
    b2v.x = tile[c8 + 4][rr]; b2v.y = tile[c8 + 5][rr];
    b2v.z = tile[c8 + 6][rr]; b2v.w = tile[c8 + 7][rr];
    uint4 pk;
    pk.x = (unsigned int)a.x | ((unsigned int)a.y << 16);
    pk.y = (unsigned int)a.z | ((unsigned int)a.w << 16);
    pk.z = (unsigned int)b2v.x | ((unsigned int)b2v.y << 16);
    pk.w = (unsigned int)b2v.z | ((unsigned int)b2v.w << 16);
    *(uint4*)(dst + (size_t)rr * R + c8) = pk;
  }
}

// ================= 2. router: one wave per token; also emits xbf =================
__global__ __launch_bounds__(256) void k_router(
    const float* __restrict__ x, const float* __restrict__ gw,
    const float* __restrict__ gb, float* __restrict__ probs_out,
    int2* __restrict__ topi, float2* __restrict__ topw,
    unsigned short* __restrict__ xbf) {
  int wave = threadIdx.x >> 6, lane = threadIdx.x & 63;
  int n = blockIdx.x * 4 + wave;
  const float4* xr = (const float4*)(x + (size_t)n * DIM);
  float4 x0 = xr[lane * 2], x1 = xr[lane * 2 + 1];
  float xf[8] = {x0.x, x0.y, x0.z, x0.w, x1.x, x1.y, x1.z, x1.w};
  uint4 pa;
  pa.x = f2bfu(xf[0]) | (f2bfu(xf[1]) << 16);
  pa.y = f2bfu(xf[2]) | (f2bfu(xf[3]) << 16);
  pa.z = f2bfu(xf[4]) | (f2bfu(xf[5]) << 16);
  pa.w = f2bfu(xf[6]) | (f2bfu(xf[7]) << 16);
  *(uint4*)(xbf + (size_t)n * DIM + lane * 8) = pa;
  float acc[8] = {0.f,0.f,0.f,0.f,0.f,0.f,0.f,0.f};
  const float4* gwr = (const float4*)gw;
#pragma unroll
  for (int j = 0; j < 8; ++j) {
    int d = lane * 8 + j;
    float4 g0 = gwr[d * 2], g1 = gwr[d * 2 + 1];
    acc[0] += xf[j] * g0.x; acc[1] += xf[j] * g0.y; acc[2] += xf[j] * g0.z; acc[3] += xf[j] * g0.w;
    acc[4] += xf[j] * g1.x; acc[5] += xf[j] * g1.y; acc[6] += xf[j] * g1.z; acc[7] += xf[j] * g1.w;
  }
#pragma unroll
  for (int o = 1; o < 64; o <<= 1)
#pragma unroll
    for (int e = 0; e < 8; ++e) acc[e] += __shfl_xor(acc[e], o, 64);
  float p[8], mx = -1e30f, s = 0.f;
#pragma unroll
  for (int e = 0; e < 8; ++e) { p[e] = acc[e] + gb[e]; mx = fmaxf(mx, p[e]); }
#pragma unroll
  for (int e = 0; e < 8; ++e) { p[e] = __expf(p[e] - mx); s += p[e]; }
  float inv = 1.f / s;
#pragma unroll
  for (int e = 0; e < 8; ++e) p[e] *= inv;
  if (lane < 8) probs_out[(size_t)n * NE + lane] = p[lane];
  if (lane == 0) {
    int i0 = 0; float v0 = p[0];
#pragma unroll
    for (int e = 1; e < 8; ++e) if (p[e] > v0) { v0 = p[e]; i0 = e; }   // first-max (jax tie rule)
    int i1 = -1; float v1 = -1.f;
#pragma unroll
    for (int e = 0; e < 8; ++e) if (e != i0 && p[e] > v1) { v1 = p[e]; i1 = e; }
    float sw = 1.f / (v0 + v1);
    topi[n] = make_int2(i0, i1);
    topw[n] = make_float2(v0 * sw, v1 * sw);
  }
}

// ================= 3. count: histogram + padded scan + tile map + pad fill =================
__global__ __launch_bounds__(1024) void k_count(
    const int2* __restrict__ topi, int* __restrict__ meta, int* __restrict__ chunk_base,
    int* __restrict__ rows, float* __restrict__ rw) {
  __shared__ int ch[32][8];
  __shared__ int tot[8], poff_s[9], tiles_s[8];
  int t = threadIdx.x;
  int g = t >> 5;
  if (t < 256) ((int*)ch)[t] = 0;
  __syncthreads();
  int c[8] = {0,0,0,0,0,0,0,0};
  int base_tok = t * 8;
#pragma unroll
  for (int i = 0; i < 8; ++i) {
    int2 e = topi[base_tok + i];
#pragma unroll
    for (int k = 0; k < 8; ++k) c[k] += (e.x == k) + (e.y == k);
  }
#pragma unroll
  for (int k = 0; k < 8; ++k) if (c[k]) atomicAdd(&ch[g][k], c[k]);
  __syncthreads();
  if (t < 8) {
    int a = 0;
#pragma unroll
    for (int b = 0; b < 32; ++b) { int v = ch[b][t]; ch[b][t] = a; a += v; }
    tot[t] = a; meta[t] = a;
  }
  __syncthreads();
  if (t == 0) {
    int a = 0, ts = 0;
#pragma unroll
    for (int e = 0; e < 8; ++e) {
      int tiles = (tot[e] + 127) >> 7;
      poff_s[e] = a; tiles_s[e] = tiles;
      meta[16 + e] = a; meta[32 + e] = ts;
      a += tiles << 7; ts += tiles;
    }
    poff_s[8] = a; meta[24] = a; meta[40] = ts;
  }
  __syncthreads();
  if (t < 256) {
    int b = t >> 3, e = t & 7;
    chunk_base[t] = poff_s[e] + ch[b][e];
  }
#pragma unroll
  for (int e = 0; e < 8; ++e) {
    int padn = (tiles_s[e] << 7) - tot[e];
    if (t < padn) {
      int s = poff_s[e] + tot[e] + t;
      rows[s] = 0; rw[s] = 0.f;
    }
  }
}

// ================= 4. slot assignment: LDS atomics only =================
__global__ __launch_bounds__(256) void k_assign(
    const int2* __restrict__ topi, const float2* __restrict__ topw,
    const int* __restrict__ chunk_base,
    int* __restrict__ rows, float* __restrict__ rw, int* __restrict__ slot_of) {
  __shared__ int lcnt[8];
  __shared__ int lbase[8];
  int t = threadIdx.x, b = blockIdx.x;
  if (t < 8) { lcnt[t] = 0; lbase[t] = chunk_base[b * 8 + t]; }
  __syncthreads();
  int n = b * 256 + t;
  int2 ei = topi[n]; float2 wv = topw[n];
  int r0 = atomicAdd(&lcnt[ei.x], 1);
  int r1 = atomicAdd(&lcnt[ei.y], 1);
  int s0 = lbase[ei.x] + r0;
  int s1 = lbase[ei.y] + r1;
  rows[s0] = n; rw[s0] = wv.x; slot_of[2 * n] = s0;
  rows[s1] = n; rw[s1] = wv.y; slot_of[2 * n + 1] = s1;
}

// ================= 5. GEMM1: h = gelu(gather(xbf) @ w1 + b1), h bf16 =================
// grid (8=nt fastest -> XCD-local weight slice, 136=tile). 128x128, BK=32,
// double-buffered async LDS (2x16KB = 32KB -> 3 blocks/CU co-residency).
// Swizzle: chunk (r, c in 0..3) at LDS slot r*4 + (c ^ ((r>>1)&3)) -> 2 lanes/bank (free).
__global__ __launch_bounds__(256) void k_gemm1(
    const unsigned short* __restrict__ xbf, const unsigned short* __restrict__ w1t,
    const float* __restrict__ b1, const int* __restrict__ meta,
    const int* __restrict__ rows, unsigned short* __restrict__ h) {
  int t = blockIdx.y;
  if (t >= meta[40]) return;
  int e = 0;
#pragma unroll
  for (int i = 1; i < 8; ++i) if (t >= meta[32 + i]) e = i;
  int mt = t - meta[32 + e];
  int row0 = meta[16 + e] + (mt << 7);
  int nt = blockIdx.x;
  __shared__ __align__(16) unsigned short As[2][4096];
  __shared__ __align__(16) unsigned short Bs[2][4096];
  int tid = threadIdx.x;
  int wave = tid >> 6, lane = tid & 63;
  int wr = wave & 1, wc = wave >> 1;
  f32x4 acc[4][4] = {};   // acc[an][am]
  const unsigned short* bBase = w1t + (size_t)e * HID * DIM + (size_t)(nt * 128) * DIM;

  // K-invariant staging addresses: 512 chunks of 8 elems (128 rows x 4 chunks), 2/thread
  const unsigned short* ga[2]; const unsigned short* gb[2];
#pragma unroll
  for (int j = 0; j < 2; ++j) {
    int s = j * 256 + tid;
    int r = s >> 2;
    int cg = ((s & 3) ^ ((r >> 1) & 3)) << 3;   // inverse swizzle -> global elem col
    ga[j] = xbf + (size_t)rows[row0 + r] * DIM + cg;
    gb[j] = bBase + (size_t)r * DIM + cg;
  }
  int ldst = (wave * 64) * 8;   // wave-uniform LDS elem base (+ lane*16B implicit)

  // prologue: stage tile 0 into buf 0
#pragma unroll
  for (int j = 0; j < 2; ++j) {
    async16(&As[0][j * 2048 + ldst], ga[j]);
    async16(&Bs[0][j * 2048 + ldst], gb[j]);
  }
  __syncthreads();

  for (int k0 = 0; k0 < DIM; k0 += 32) {
    int cur = (k0 >> 5) & 1, nxt = cur ^ 1;
    if (k0 + 32 < DIM) {
#pragma unroll
      for (int j = 0; j < 2; ++j) {
        async16(&As[nxt][j * 2048 + ldst], ga[j] + k0 + 32);
        async16(&Bs[nxt][j * 2048 + ldst], gb[j] + k0 + 32);
      }
    }
    {
      int ca = lane >> 4;                  // quad's K-chunk (K=32 = 4 chunks of 8)
      short8 tf[4], wf[4];
#pragma unroll
      for (int am = 0; am < 4; ++am) {
        int ra = wr * 64 + am * 16 + (lane & 15);
        tf[am] = *(const short8*)&As[cur][(ra * 4 + (ca ^ ((ra >> 1) & 3))) * 8];
      }
#pragma unroll
      for (int an = 0; an < 4; ++an) {
        int rb = wc * 64 + an * 16 + (lane & 15);
        wf[an] = *(const short8*)&Bs[cur][(rb * 4 + (ca ^ ((rb >> 1) & 3))) * 8];
      }
#pragma unroll
      for (int an = 0; an < 4; ++an)
#pragma unroll
        for (int am = 0; am < 4; ++am)
          acc[an][am] = __builtin_amdgcn_mfma_f32_16x16x32_bf16(wf[an], tf[am], acc[an][am], 0, 0, 0);
    }
    __syncthreads();   // drains lgkm (cur reads done) + vmcnt (prefetch arrived)
  }
  // epilogue: lane holds token row (lane&15) x 4 consecutive cols (quad*4..+3)
  int ml = lane & 15, q = lane >> 4;
#pragma unroll
  for (int am = 0; am < 4; ++am) {
    int slot_r = row0 + wr * 64 + am * 16 + ml;
    unsigned short* hrow = h + (size_t)slot_r * HID;
#pragma unroll
    for (int an = 0; an < 4; ++an) {
      int colb = nt * 128 + wc * 64 + an * 16 + q * 4;
      float4 bias = *(const float4*)&b1[e * HID + colb];
      f32x4 v = acc[an][am];
      float g0 = gelu_f(v[0] + bias.x);
      float g1 = gelu_f(v[1] + bias.y);
      float g2 = gelu_f(v[2] + bias.z);
      float g3 = gelu_f(v[3] + bias.w);
      uint2 pk;
      pk.x = f2bfu(g0) | (f2bfu(g1) << 16);
      pk.y = f2bfu(g2) | (f2bfu(g3) << 16);
      *(uint2*)(hrow + colb) = pk;
    }
  }
}

// ================= 6. GEMM2: y = (h @ w2 + b2) * weight, y bf16 =================
// grid (4=nt fastest, 136=tile). K = HID = 1024, BK=32 dbuf.
__global__ __launch_bounds__(256) void k_gemm2(
    const unsigned short* __restrict__ h, const unsigned short* __restrict__ w2t,
    const float* __restrict__ b2, const int* __restrict__ meta,
    const float* __restrict__ rw, unsigned short* __restrict__ y) {
  int t = blockIdx.y;
  if (t >= meta[40]) return;
  int e = 0;
#pragma unroll
  for (int i = 1; i < 8; ++i) if (t >= meta[32 + i]) e = i;
  int mt = t - meta[32 + e];
  int row0 = meta[16 + e] + (mt << 7);
  int nt = blockIdx.x;
  __shared__ __align__(16) unsigned short As[2][4096];
  __shared__ __align__(16) unsigned short Bs[2][4096];
  int tid = threadIdx.x;
  int wave = tid >> 6, lane = tid & 63;
  int wr = wave & 1, wc = wave >> 1;
  f32x4 acc[4][4] = {};   // acc[an][am]
  const unsigned short* aBase = h + (size_t)row0 * HID;
  const unsigned short* bBase = w2t + (size_t)e * DIM * HID + (size_t)(nt * 128) * HID;

  const unsigned short* ga[2]; const unsigned short* gb[2];
#pragma unroll
  for (int j = 0; j < 2; ++j) {
    int s = j * 256 + tid;
    int r = s >> 2;
    int cg = ((s & 3) ^ ((r >> 1) & 3)) << 3;
    ga[j] = aBase + (size_t)r * HID + cg;
    gb[j] = bBase + (size_t)r * HID + cg;
  }
  int ldst = (wave * 64) * 8;

#pragma unroll
  for (int j = 0; j < 2; ++j) {
    async16(&As[0][j * 2048 + ldst], ga[j]);
    async16(&Bs[0][j * 2048 + ldst], gb[j]);
  }
  __syncthreads();

  for (int k0 = 0; k0 < HID; k0 += 32) {
    int cur = (k0 >> 5) & 1, nxt = cur ^ 1;
    if (k0 + 32 < HID) {
#pragma unroll
      for (int j = 0; j < 2; ++j) {
        async16(&As[nxt][j * 2048 + ldst], ga[j] + k0 + 32);
        async16(&Bs[nxt][j * 2048 + ldst], gb[j] + k0 + 32);
      }
    }
    {
      int ca = lane >> 4;
      short8 tf[4], wf[4];
#pragma unroll
      for (int am = 0; am < 4; ++am) {
        int ra = wr * 64 + am * 16 + (lane & 15);
        tf[am] = *(const short8*)&As[cur][(ra * 4 + (ca ^ ((ra >> 1) & 3))) * 8];
      }
#pragma unroll
      for (int an = 0; an < 4; ++an) {
        int rb = wc * 64 + an * 16 + (lane & 15);
        wf[an] = *(const short8*)&Bs[cur][(rb * 4 + (ca ^ ((rb >> 1) & 3))) * 8];
      }
#pragma unroll
      for (int an = 0; an < 4; ++an)
#pragma unroll
        for (int am = 0; am < 4; ++am)
          acc[an][am] = __builtin_amdgcn_mfma_f32_16x16x32_bf16(wf[an], tf[am], acc[an][am], 0, 0, 0);
    }
    __syncthreads();
  }
  int ml = lane & 15, q = lane >> 4;
#pragma unroll
  for (int am = 0; am < 4; ++am) {
    int slot_r = row0 + wr * 64 + am * 16 + ml;
    float w = rw[slot_r];
    unsigned short* yrow = y + (size_t)slot_r * DIM;
#pragma unroll
    for (int an = 0; an < 4; ++an) {
      int colb = nt * 128 + wc * 64 + an * 16 + q * 4;
      float4 bias = *(const float4*)&b2[e * DIM + colb];
      f32x4 v = acc[an][am];
      uint2 pk;
      pk.x = f2bfu((v[0] + bias.x) * w) | (f2bfu((v[1] + bias.y) * w) << 16);
      pk.y = f2bfu((v[2] + bias.z) * w) | (f2bfu((v[3] + bias.w) * w) << 16);
      *(uint2*)(yrow + colb) = pk;
    }
  }
}

// ================= 7. combine: out[n] = y[slot0] + y[slot1] (bf16 -> fp32) =================
__global__ __launch_bounds__(256) void k_combine(
    const unsigned short* __restrict__ y, const int* __restrict__ slot_of,
    float* __restrict__ out) {
  int t = blockIdx.x * 256 + threadIdx.x;
  int n = t >> 6, c = (t & 63) << 3;
  int s0 = slot_of[2 * n], s1 = slot_of[2 * n + 1];
  uint4 u0 = *(const uint4*)(y + (size_t)s0 * DIM + c);
  uint4 u1 = *(const uint4*)(y + (size_t)s1 * DIM + c);
  float4 o0, o1;
  o0.x = bf2f(u0.x) + bf2f(u1.x); o0.y = bf2f(u0.x >> 16) + bf2f(u1.x >> 16);
  o0.z = bf2f(u0.y) + bf2f(u1.y); o0.w = bf2f(u0.y >> 16) + bf2f(u1.y >> 16);
  o1.x = bf2f(u0.z) + bf2f(u1.z); o1.y = bf2f(u0.z >> 16) + bf2f(u1.z >> 16);
  o1.z = bf2f(u0.w) + bf2f(u1.w); o1.w = bf2f(u0.w >> 16) + bf2f(u1.w >> 16);
  *(float4*)(out + (size_t)n * DIM + c) = o0;
  *(float4*)(out + (size_t)n * DIM + c + 4) = o1;
}

// ================= launch =================
extern "C" void kernel_launch(void* const* d_in, const int* in_sizes, int n_in,
                              void* d_out, int out_size, void* d_ws, size_t ws_size,
                              hipStream_t stream) {
  const float* x  = (const float*)d_in[0];
  const float* gw = (const float*)d_in[1];
  const float* gb = (const float*)d_in[2];
  const float* w1 = (const float*)d_in[3];
  const float* b1 = (const float*)d_in[4];
  const float* w2 = (const float*)d_in[5];
  const float* b2 = (const float*)d_in[6];
  float* out = (float*)d_out;
  char* ws = (char*)d_ws;

  unsigned short* w1t = (unsigned short*)(ws + W1T_OFF);
  unsigned short* w2t = (unsigned short*)(ws + W2T_OFF);
  unsigned short* h   = (unsigned short*)(ws + H_OFF);
  unsigned short* y   = (unsigned short*)(ws + Y_OFF);
  unsigned short* xbf = (unsigned short*)(ws + XBF_OFF);
  int2*   topi    = (int2*)(ws + TOPI_OFF);
  float2* topw    = (float2*)(ws + TOPW_OFF);
  int*    slot_of = (int*)(ws + SLOT_OFF);
  int*    rows    = (int*)(ws + ROWS_OFF);
  float*  rw      = (float*)(ws + RW_OFF);
  int*    meta    = (int*)(ws + CNT_OFF);
  int*    chunk_base = meta + 64;
  float*  probs   = out + (size_t)N_TOK * DIM;

  k_transpose<<<dim3(2048), dim3(256), 0, stream>>>(w1, w2, w1t, w2t);
  k_router   <<<dim3(2048), dim3(256), 0, stream>>>(x, gw, gb, probs, topi, topw, xbf);
  k_count    <<<dim3(1),    dim3(1024), 0, stream>>>(topi, meta, chunk_base, rows, rw);
  k_assign   <<<dim3(32),   dim3(256), 0, stream>>>(topi, topw, chunk_base, rows, rw, slot_of);
  k_gemm1    <<<dim3(8, 136), dim3(256), 0, stream>>>(xbf, w1t, b1, meta, rows, h);
  k_gemm2    <<<dim3(4, 136), dim3(256), 0, stream>>>(h, w2t, b2, meta, rw, y);
  k_combine  <<<dim3(2048), dim3(256), 0, stream>>>(y, slot_of, out);
}